// Round 12
// baseline (158.937 us; speedup 1.0000x reference)
//
#include <hip/hip_runtime.h>

// SIRD RK4, round 12: producer/consumer refinement.
// R11 accounting (117.7 cyc/tstep = 29.4 slots @ the hard 4 cyc/slot lone-wave
// cadence): 22 RK4 core + 1 ds_write + 2 pair-packing movs + loop + ~3
// barrier-drain. This round: (1) state carried as float2 so ds_write_b64
// writes the allocated pair directly (no movs); (2) KSEG 32->64 halves
// barrier count (LDS 64 KiB double-buffer, 1 block/CU so occupancy moot);
// (3) consumer emits orow[0] from the pre-step slot uniformly.
//
// State (sigma, I), sigma = c*S: d(sigma) = -c*(sigma*I), dI = fma(-gm,I,m).
// D from RK4-preserved invariant: D = fma(-kD/c, sigma, fma(-kD, I, kD*N)).
// Slot k of segment seg holds PRE-step state at t = seg*KSEG + k.

#define N_POP 1.0e7f
#define T_PTS 2048
#define KSEG 64
#define NSEG (T_PTS / KSEG)   // 32 segments

__global__ __launch_bounds__(128, 1) void sird_kernel(const float* __restrict__ alpha,
                                                      float* __restrict__ out) {
    const int lane = threadIdx.x & 63;
    const int wave = threadIdx.x >> 6;        // 0 = producer, 1 = consumer
    const int s = blockIdx.x * 64 + lane;     // scenario (same for both waves)

    __shared__ float2 buf[2][KSEG][64];       // 64 KiB

    const float beta  = alpha[s * 3 + 0];
    const float gamma = alpha[s * 3 + 1];
    const float mu    = alpha[s * 3 + 2];

    const float c    = beta * (1.0f / N_POP);
    const float gm   = gamma + mu;
    const float ngm  = -gm;
    const float h2   = 0.5f;                  // h/2, h = 1
    const float nch2 = -0.5f * c;             // -c*h/2
    const float nch  = -c;                    // -c*h
    const float w    = 1.0f / 6.0f;
    const float nwc  = -c * (1.0f / 6.0f);
    const float kD   = mu / gm;               // gamma,mu > 0 a.s.
    const float kDN  = kD * (float)N_POP;
    const float nkc  = -kD / c;
    const float nk   = -kD;

    float2 st = make_float2(c * (N_POP - 1.0f), 1.0f);   // (sigma, I), adjacent pair

    float2* __restrict__ orow = (float2*)out + (size_t)s * T_PTS;

    for (int seg = 0; seg <= NSEG; ++seg) {
        if (wave == 0) {
            if (seg < NSEG) {
                float2* bp = &buf[seg & 1][0][lane];
#pragma unroll
                for (int k = 0; k < KSEG; ++k) {
                    bp[k * 64] = st;                      // pre-step state, ds_write_b64
                    // RK4 step h=1, 22 VALU slots, in-place on st.x/st.y
                    const float m1 = st.x * st.y;
                    const float g1 = __builtin_fmaf(ngm, st.y, m1);
                    const float s2 = __builtin_fmaf(nch2, m1, st.x);
                    const float i2 = __builtin_fmaf(h2, g1, st.y);
                    const float m2 = s2 * i2;
                    const float g2 = __builtin_fmaf(ngm, i2, m2);
                    const float s3 = __builtin_fmaf(nch2, m2, st.x);
                    const float i3 = __builtin_fmaf(h2, g2, st.y);
                    const float m3 = s3 * i3;
                    const float g3 = __builtin_fmaf(ngm, i3, m3);
                    const float s4 = __builtin_fmaf(nch, m3, st.x);
                    const float i4 = st.y + g3;
                    const float m4 = s4 * i4;
                    const float g4 = __builtin_fmaf(ngm, i4, m4);
                    float tm = __builtin_fmaf(2.0f, m2, m1);
                    tm = __builtin_fmaf(2.0f, m3, tm);
                    st.x = __builtin_fmaf(nwc, m4, __builtin_fmaf(nwc, tm, st.x));
                    float tg = __builtin_fmaf(2.0f, g2, g1);
                    tg = __builtin_fmaf(2.0f, g3, tg);
                    st.y = __builtin_fmaf(w, g4, __builtin_fmaf(w, tg, st.y));
                }
            }
        } else {
            if (seg >= 1) {
                const float2* qp = &buf[(seg - 1) & 1][0][lane];
                float2* op = orow + (size_t)(seg - 1) * KSEG;
#pragma unroll
                for (int k = 0; k < KSEG; ++k) {
                    const float2 v = qp[k * 64];          // (sigma_t, I_t)
                    const float Dv = __builtin_fmaf(nkc, v.x,
                                     __builtin_fmaf(nk, v.y, kDN));
                    op[k] = make_float2(v.y, Dv);
                }
            }
        }
        __syncthreads();
    }
}

extern "C" void kernel_launch(void* const* d_in, const int* in_sizes, int n_in,
                              void* d_out, int out_size, void* d_ws, size_t ws_size,
                              hipStream_t stream) {
    const float* alpha = (const float*)d_in[0];
    float* out = (float*)d_out;
    sird_kernel<<<dim3(T_PTS / 64), dim3(128), 0, stream>>>(alpha, out);
}

// Round 13
// 153.704 us; speedup vs baseline: 1.0340x; 1.0340x over previous
//
#include <hip/hip_runtime.h>

// SIRD RK4, round 13: stride-2 handoff, SoA b32 LDS writes.
// Established: lone-wave issue cadence 4 cyc/slot (hard); RK4 core floor =
// 22 slots (g-elimination variant also 22). R11 producer measured ~29.4
// slots/tstep: 22 core + ds_write_b64 + 2 packing movs + ds/barrier
// surcharge. This round the producer writes state only every 2nd tstep as
// TWO ds_write_b32 (scalar regs -> LDS directly, no packing), and the
// consumer recomputes the intermediate RK4 step itself (bit-identical fp32)
// before applying the D-invariant and storing both rows. Producer:
// ~23.5 slots/tstep; consumer ~16/tstep (hidden). Barriers halve (segment
// spans 64 tsteps).
//
// State (sigma, I), sigma = c*S: d(sigma) = -c*(sigma*I), dI = fma(-gm,I,m).
// D from RK4-preserved invariant: D = fma(-kD/c, sigma, fma(-kD, I, kD*N)).

#define N_POP 1.0e7f
#define T_PTS 2048
#define KSEG 32                  // LDS slots per segment
#define SEG_T (KSEG * 2)         // tsteps covered per segment (stride 2)
#define NSEG (T_PTS / SEG_T)     // 32 segments

// One RK4 step (h=1), 22 VALU slots, updates SG and IV in place.
#define RK4_STEP(SG, IV)                                                     \
    do {                                                                     \
        const float m1 = (SG) * (IV);                                        \
        const float g1 = __builtin_fmaf(ngm, (IV), m1);                      \
        const float s2 = __builtin_fmaf(nch2, m1, (SG));                     \
        const float i2 = __builtin_fmaf(h2, g1, (IV));                       \
        const float m2 = s2 * i2;                                            \
        const float g2 = __builtin_fmaf(ngm, i2, m2);                        \
        const float s3 = __builtin_fmaf(nch2, m2, (SG));                     \
        const float i3 = __builtin_fmaf(h2, g2, (IV));                       \
        const float m3 = s3 * i3;                                            \
        const float g3 = __builtin_fmaf(ngm, i3, m3);                        \
        const float s4 = __builtin_fmaf(nch, m3, (SG));                      \
        const float i4 = (IV) + g3;                                          \
        const float m4 = s4 * i4;                                            \
        const float g4 = __builtin_fmaf(ngm, i4, m4);                        \
        float tm = __builtin_fmaf(2.0f, m2, m1);                             \
        tm = __builtin_fmaf(2.0f, m3, tm);                                   \
        (SG) = __builtin_fmaf(nwc, m4, __builtin_fmaf(nwc, tm, (SG)));       \
        float tg = __builtin_fmaf(2.0f, g2, g1);                             \
        tg = __builtin_fmaf(2.0f, g3, tg);                                   \
        (IV) = __builtin_fmaf(w, g4, __builtin_fmaf(w, tg, (IV)));           \
    } while (0)

__global__ __launch_bounds__(128, 1) void sird_kernel(const float* __restrict__ alpha,
                                                      float* __restrict__ out) {
    const int lane = threadIdx.x & 63;
    const int wave = threadIdx.x >> 6;        // 0 = producer, 1 = consumer
    const int s = blockIdx.x * 64 + lane;     // scenario (same for both waves)

    // SoA, double-buffered: [buf][var][slot][lane], var 0=sigma 1=I. 32 KiB.
    __shared__ float buf[2][2][KSEG][64];

    const float beta  = alpha[s * 3 + 0];
    const float gamma = alpha[s * 3 + 1];
    const float mu    = alpha[s * 3 + 2];

    const float c    = beta * (1.0f / N_POP);
    const float gm   = gamma + mu;
    const float ngm  = -gm;
    const float h2   = 0.5f;                  // h/2, h = 1
    const float nch2 = -0.5f * c;             // -c*h/2
    const float nch  = -c;                    // -c*h
    const float w    = 1.0f / 6.0f;
    const float nwc  = -c * (1.0f / 6.0f);
    const float kD   = mu / gm;               // gamma,mu > 0 a.s.
    const float kDN  = kD * (float)N_POP;
    const float nkc  = -kD / c;
    const float nk   = -kD;

    float sg = c * (N_POP - 1.0f);            // sigma = c*S
    float I  = 1.0f;

    float2* __restrict__ orow = (float2*)out + (size_t)s * T_PTS;

    for (int seg = 0; seg <= NSEG; ++seg) {
        if (wave == 0) {
            if (seg < NSEG) {
                float* bsg = &buf[seg & 1][0][0][lane];
                float* bI  = &buf[seg & 1][1][0][lane];
#pragma unroll
                for (int k = 0; k < KSEG; ++k) {
                    bsg[k * 64] = sg;          // ds_write_b32, immediate offset
                    bI [k * 64] = I;
                    RK4_STEP(sg, I);           // even -> odd
                    RK4_STEP(sg, I);           // odd  -> next even
                }
            }
        } else {
            if (seg >= 1) {
                const float* qsg = &buf[(seg - 1) & 1][0][0][lane];
                const float* qI  = &buf[(seg - 1) & 1][1][0][lane];
                float2* op = orow + (size_t)(seg - 1) * SEG_T;
#pragma unroll
                for (int k = 0; k < KSEG; ++k) {
                    float sgv = qsg[k * 64];
                    float Iv  = qI [k * 64];
                    const float D0 = __builtin_fmaf(nkc, sgv,
                                     __builtin_fmaf(nk, Iv, kDN));
                    op[2 * k] = make_float2(Iv, D0);
                    RK4_STEP(sgv, Iv);         // bit-identical recompute of odd t
                    const float D1 = __builtin_fmaf(nkc, sgv,
                                     __builtin_fmaf(nk, Iv, kDN));
                    op[2 * k + 1] = make_float2(Iv, D1);
                }
            }
        }
        __syncthreads();
    }
}

extern "C" void kernel_launch(void* const* d_in, const int* in_sizes, int n_in,
                              void* d_out, int out_size, void* d_ws, size_t ws_size,
                              hipStream_t stream) {
    const float* alpha = (const float*)d_in[0];
    float* out = (float*)d_out;
    sird_kernel<<<dim3(T_PTS / 64), dim3(128), 0, stream>>>(alpha, out);
}